// Round 8
// baseline (255.533 us; speedup 1.0000x reference)
//
#include <hip/hip_runtime.h>

// Problem constants: x [4, 64, 64, 128] fp32
constexpr int C       = 128;
constexpr int N       = 4096;
constexpr int BATCH   = 4;
constexpr int TOTROWS = BATCH * N;            // 16384
constexpr float SCALE = 0.08838834764831845f; // 1/sqrt(128)
constexpr float LOG2E = 1.44269504088896340736f;

constexpr int BK = 64;     // keys per iteration

typedef __attribute__((ext_vector_type(8))) short        bf16x8;
typedef __attribute__((ext_vector_type(4))) float        f32x4;
typedef __attribute__((ext_vector_type(2))) unsigned int u32x2;

__device__ inline unsigned short f2bf(float f) {   // RNE float->bf16 (scalar)
    unsigned int u = __float_as_uint(f);
    return (unsigned short)((u + 0x7FFFu + ((u >> 16) & 1u)) >> 16);
}
// packed RNE f32x2 -> bf16x2 in ONE instruction
__device__ inline unsigned int cvtpk(float a, float b) {
    unsigned int r;
    asm("v_cvt_pk_bf16_f32 %0, %1, %2" : "=v"(r) : "v"(a), "v"(b));
    return r;
}
__device__ inline float bf2f(unsigned int u) {
    return __uint_as_float(u << 16);
}
// bare v_exp_f32 (q is pre-scaled by LOG2E; no OCML range-fixup needed)
__device__ inline float fexp2(float x) {
#if __has_builtin(__builtin_amdgcn_exp2f)
    return __builtin_amdgcn_exp2f(x);
#else
    float r; asm("v_exp_f32 %0, %1\n\ts_nop 0" : "=v"(r) : "v"(x)); return r;
#endif
}
// async global->LDS DMA, 16B per lane; LDS dest = wave-uniform base + lane*16
__device__ inline void dma16(const void* g, void* l) {
    __builtin_amdgcn_global_load_lds(
        (const __attribute__((address_space(1))) void*)g,
        (__attribute__((address_space(3))) void*)l, 16, 0, 0);
}

// ---------------------------------------------------------------------------
// round-21 wprep: one-time W transpose (3 blocks x 256 thr), now with
// CONTIGUOUS 16B stores. r7's version issued 64 scattered 2-byte global
// stores per thread (each lane a different 64B sector -> worst-case 64
// transactions/instr). Inverted loop: each thread produces 8 full granules:
//   granule g of row o holds W[i][o], i = ((g&8)|((g&7)^xr))*8+e, xr=(o>>2)&7
// reads are 8 strided scalar loads of L2-hot W; write is ONE uint4.
// Mapping identical to r7's (verified): dst[o*128 + g*8 + e] = bf16(W[i][o]*s).
// ---------------------------------------------------------------------------
__global__ __launch_bounds__(256)
void wprep_kernel(const float* __restrict__ Wq, const float* __restrict__ Wk,
                  const float* __restrict__ Wv, unsigned short* __restrict__ wt)
{
    const int mat = blockIdx.x;
    const float* W = (mat == 0) ? Wq : (mat == 1) ? Wk : Wv;
    const float  s = (mat == 0) ? SCALE * LOG2E : 1.0f;
    unsigned short* dst = wt + mat * 16384;

    const int t  = threadIdx.x;
    const int o  = t >> 1;             // output chan (W^T row), 0..127
    const int g0 = (t & 1) * 8;        // granule half
    const int xr = (o >> 2) & 7;
    #pragma unroll
    for (int gg = 0; gg < 8; ++gg) {
        const int g   = g0 + gg;
        const int ihi = (g & 8) | ((g & 7) ^ xr);
        const int i0  = ihi << 3;
        union { unsigned short u16[8]; uint4 v; } buf;
        #pragma unroll
        for (int e = 0; e < 8; ++e)
            buf.u16[e] = f2bf(W[(i0 + e) * 128 + o] * s);
        *reinterpret_cast<uint4*>(&dst[o * 128 + g * 8]) = buf.v;
    }
}

// ---------------------------------------------------------------------------
// round-20 qkv (verified r7): 256 blocks, x fragments loaded ONCE and reused
// for all 3 matrices; W^T images double-buffer-DMA'd from wprep's output.
// ---------------------------------------------------------------------------
__global__ __launch_bounds__(256, 2)
void qkv_kernel(const float* __restrict__ x, const unsigned short* __restrict__ wt,
                const float* __restrict__ bq, const float* __restrict__ bk,
                const float* __restrict__ bv,
                unsigned short* __restrict__ qo,
                unsigned short* __restrict__ ko,
                unsigned short* __restrict__ vt)
{
    __shared__ __align__(16) unsigned short wl[2][16384];   // 65536 B

    const int tid  = threadIdx.x;
    const int lane = tid & 63;
    const int lo   = lane & 15;
    const int quad = lane >> 4;
    const long rowbase = (long)blockIdx.x * 64 + (tid >> 6) * 16;

    // x fragments (row = rowbase+lo, k = ks*32+quad*8), fp32->bf16 in regs.
    bf16x8 xf[4];
    {
        const float4* xr = reinterpret_cast<const float4*>(&x[(rowbase + lo) * C]);
        #pragma unroll
        for (int ks = 0; ks < 4; ++ks) {
            float4 a  = xr[ks * 8 + quad * 2];
            float4 b2 = xr[ks * 8 + quad * 2 + 1];
            union { bf16x8 v; unsigned int u[4]; } cv;
            cv.u[0] = cvtpk(a.x, a.y);
            cv.u[1] = cvtpk(a.z, a.w);
            cv.u[2] = cvtpk(b2.x, b2.y);
            cv.u[3] = cvtpk(b2.z, b2.w);
            xf[ks] = cv.v;
        }
    }

    auto stageW = [&](int mat, int bufi) {
        const char* src = (const char*)(wt + mat * 16384);
        #pragma unroll
        for (int c = 0; c < 8; ++c)
            dma16(src + (c * 256 + tid) * 16, &wl[bufi][(c * 256 + tid) * 8]);
    };

    stageW(0, 0);
    __syncthreads();                  // drains DMA (vmcnt 0)

    #pragma unroll
    for (int mat = 0; mat < 3; ++mat) {
        if (mat < 2) stageW(mat + 1, (mat + 1) & 1);
        const unsigned short* wb = wl[mat & 1];

        if (mat < 2) {
            // q/k: D[m=outchan][n=row], A=W^T frag, B=xf -> row-major store
            f32x4 acc[8] = {};
            #pragma unroll
            for (int ks = 0; ks < 4; ++ks)
                #pragma unroll
                for (int mt = 0; mt < 8; ++mt) {
                    const int rr = mt * 16 + lo;
                    bf16x8 wf = *reinterpret_cast<const bf16x8*>(
                        &wb[rr * 128 + (((ks * 4 + quad) ^ ((rr >> 2) & 7)) << 3)]);
                    acc[mt] = __builtin_amdgcn_mfma_f32_16x16x32_bf16(
                        wf, xf[ks], acc[mt], 0, 0, 0);
                }
            const float* bias = (mat == 0) ? bq : bk;
            const float  s    = (mat == 0) ? SCALE * LOG2E : 1.0f;
            unsigned short* out = (mat == 0) ? qo : ko;
            long row = rowbase + lo;
            #pragma unroll
            for (int mt = 0; mt < 8; ++mt) {
                float4 bb = *reinterpret_cast<const float4*>(&bias[mt * 16 + quad * 4]);
                u32x2 w;
                w[0] = cvtpk(acc[mt][0] + bb.x * s, acc[mt][1] + bb.y * s);
                w[1] = cvtpk(acc[mt][2] + bb.z * s, acc[mt][3] + bb.w * s);
                *reinterpret_cast<u32x2*>(&out[row * C + mt * 16 + quad * 4]) = w;
            }
        } else {
            // v: D[m=row][n=chan], A=xf, B=W^T frag -> tiled transposed store
            f32x4 acc[8] = {};
            #pragma unroll
            for (int ks = 0; ks < 4; ++ks)
                #pragma unroll
                for (int ct = 0; ct < 8; ++ct) {
                    const int rr = ct * 16 + lo;
                    bf16x8 wf = *reinterpret_cast<const bf16x8*>(
                        &wb[rr * 128 + (((ks * 4 + quad) ^ ((rr >> 2) & 7)) << 3)]);
                    acc[ct] = __builtin_amdgcn_mfma_f32_16x16x32_bf16(
                        xf[ks], wf, acc[ct], 0, 0, 0);
                }
            const int b = (int)(rowbase >> 12);
            const int nbase = (int)(rowbase & (N - 1));
            const int n0   = nbase + quad * 4;
            const int nblk = n0 >> 6;
            #pragma unroll
            for (int ct = 0; ct < 8; ++ct) {
                int chan = ct * 16 + lo;
                float bb = bv[chan];
                u32x2 w;
                w[0] = cvtpk(acc[ct][0] + bb, acc[ct][1] + bb);
                w[1] = cvtpk(acc[ct][2] + bb, acc[ct][3] + bb);
                *reinterpret_cast<u32x2*>(
                    &vt[(((size_t)b * 64 + nblk) * 128 + chan) * 64 + (n0 & 63)]) = w;
            }
        }
        __syncthreads();   // next-buf DMA drained; all waves done with wb
    }
}

// ---------------------------------------------------------------------------
// Flash attention — r3-verified body (46.8us), UNCHANGED through the opart
// epilogue. round-21 adds a SPLIT-K FIXUP TAIL that replaces combine_kernel:
// after opart/lpart stores: __threadfence (release), barrier, tid0 atomicAdd
// cnt[b*32+qt]; the block seeing old==nspl-1 acquires and combines its 128
// rows (opart slices are L2/MALL-hot, not re-fetched from HBM ~50us later).
// Device-scope atomics + fences per guide G12/G16 (m20). Counter zeroed per
// launch via hipMemsetAsync in kernel_launch (graph-capturable).
// ---------------------------------------------------------------------------
__global__ __launch_bounds__(256, 2)
void attn_kernel(const unsigned short* __restrict__ q,
                 const unsigned short* __restrict__ k,
                 const unsigned short* __restrict__ vt,
                 unsigned short* __restrict__ opart,
                 float* __restrict__ lpart,
                 const float* __restrict__ x,
                 float* __restrict__ out,
                 unsigned int* __restrict__ cnt)
{
    // buffer A: K0 @0 (8192), V0 @8192 (8192), pad to 17472 shorts;
    //           reused as O-bounce (128 x 136 shorts) in the epilogue
    __shared__ __align__(16) unsigned short smA[17472];  // 34944 B
    __shared__ __align__(16) unsigned short smB[16384];  // 32768 B (K1,V1)
    __shared__ __align__(16) unsigned short smP[4096];   //  8192 B (4 waves x 32x32)
    __shared__ unsigned int lastflag;

    const int tid  = threadIdx.x;
    const int wv   = tid >> 6;          // 0..3
    const int lane = tid & 63;
    const int lo   = lane & 15;
    const int quad = lane >> 4;

    const int nspl = (int)(gridDim.x >> 7);      // 512 -> 4, 256 -> 2
    const int id   = blockIdx.x;
    int b, sl, qt;
    if (nspl == 4) {         // id%8 = b*2 + (sl&1): pins (batch,parity) to XCD
        b  = (id >> 1) & 3;
        sl = (id & 1) | (((id >> 3) & 1) << 1);
        qt = id >> 4;        // 0..31
    } else {
        b  = (id >> 1) & 3;
        sl = id & 1;
        qt = id >> 3;
    }
    const int NIT  = (N / nspl) / BK;            // 16 (nspl=4), even
    const int koff = sl * (N / nspl);

    const int    rowb  = b * N + qt * 128;       // block's first q-row (global)
    const size_t qrow0 = (size_t)rowb + wv * 32; // wave's first q-row
    const char* kb8 = (const char*)(k  + ((size_t)b * N + koff) * C);
    const char* vb8 = (const char*)(vt + ((size_t)b * 64 + (koff >> 6)) * (size_t)(128 * 64));

    unsigned short* PW = smP + wv * 1024;        // wave-private 32x32 P tile

    // Q fragments (B operand): qf[nt][ks], row = qrow0 + nt*16 + lo
    bf16x8 qf[2][4];
    #pragma unroll
    for (int nt = 0; nt < 2; ++nt)
        #pragma unroll
        for (int ks = 0; ks < 4; ++ks)
            qf[nt][ks] = *reinterpret_cast<const bf16x8*>(
                &q[(qrow0 + nt * 16 + lo) * C + ks * 32 + quad * 8]);

    // DMA source offsets (bytes, kt-invariant), pre-swizzled so that linear
    // LDS granule G holds swizzled global granule; reads apply the same XOR.
    int offK[4], offV[4];
    #pragma unroll
    for (int c = 0; c < 4; ++c) {
        int G  = (wv * 4 + c) * 64 + lane;
        int kr = G >> 4;                              // K: 64 rows x 16 granules
        offK[c] = kr * 256 + (((G & 15) ^ (kr & 7)) << 4);
        int vr = G >> 3;                              // V: 128 rows x 8 granules
        offV[c] = vr * 128 + (((G & 7) ^ (vr & 7)) << 4);
    }

    auto stage = [&](int kt, unsigned short* dstKV) {
        const char* kt8 = kb8 + kt * 16384;
        const char* vt8 = vb8 + kt * 16384;
        #pragma unroll
        for (int c = 0; c < 4; ++c)
            dma16(kt8 + offK[c], dstKV + (wv * 4 + c) * 512);
        #pragma unroll
        for (int c = 0; c < 4; ++c)
            dma16(vt8 + offV[c], dstKV + 8192 + (wv * 4 + c) * 512);
    };

    float l_i[2] = { 0.f, 0.f };
    f32x4 ot[2][8] = {};   // O^T: col = qrow nt*16+lo, regs = chan ct*16+quad*4+r

    auto body = [&](const unsigned short* base) {
        const unsigned short* kc = base;
        const unsigned short* vc = base + 8192;

        // ---- S^T = K.Q^T : st[mt][nt], key = mt*16+quad*4+r, qrow = nt*16+lo
        f32x4 st[4][2] = {};
        #pragma unroll
        for (int ks = 0; ks < 4; ++ks)
            #pragma unroll
            for (int mt = 0; mt < 4; ++mt) {
                const bf16x8 kf = *reinterpret_cast<const bf16x8*>(
                    &kc[(mt * 16 + lo) * 128 + (((ks * 4 + quad) ^ (lo & 7)) << 3)]);
                #pragma unroll
                for (int nt = 0; nt < 2; ++nt)
                    st[mt][nt] = __builtin_amdgcn_mfma_f32_16x16x32_bf16(
                        kf, qf[nt][ks], st[mt][nt], 0, 0, 0);
            }

        // ---- per 32-key half: softmax numerator (fixed m=0) + PV ----
        #pragma unroll
        for (int h = 0; h < 2; ++h) {
            #pragma unroll
            for (int nt = 0; nt < 2; ++nt) {
                const int prow = nt * 16 + lo;
                float ps = 0.f;
                #pragma unroll
                for (int m = 0; m < 2; ++m) {
                    f32x4 s = st[2 * h + m][nt];
                    float p0 = fexp2(s[0]);
                    float p1 = fexp2(s[1]);
                    float p2 = fexp2(s[2]);
                    float p3 = fexp2(s[3]);
                    ps += (p0 + p1) + (p2 + p3);
                    u32x2 w;
                    w[0] = cvtpk(p0, p1);
                    w[1] = cvtpk(p2, p3);
                    *reinterpret_cast<u32x2*>(
                        &PW[prow * 32 + (((2 * m + (quad >> 1)) ^ (prow & 3)) << 3)
                            + (quad & 1) * 4]) = w;
                }
                l_i[nt] += ps;
            }
            bf16x8 pf[2];
            #pragma unroll
            for (int nt = 0; nt < 2; ++nt) {
                const int prow = nt * 16 + lo;
                pf[nt] = *reinterpret_cast<const bf16x8*>(
                    &PW[prow * 32 + ((quad ^ (prow & 3)) << 3)]);
            }
            #pragma unroll
            for (int ct = 0; ct < 8; ++ct) {
                const bf16x8 vf = *reinterpret_cast<const bf16x8*>(
                    &vc[(ct * 16 + lo) * 64 + (((h * 4 + quad) ^ (lo & 7)) << 3)]);
                #pragma unroll
                for (int nt = 0; nt < 2; ++nt)
                    ot[nt][ct] = __builtin_amdgcn_mfma_f32_16x16x32_bf16(
                        vf, pf[nt], ot[nt][ct], 0, 0, 0);
            }
        }
    };

    // ---- pipeline: stage next tile (async DMA) || compute current ----
    stage(0, smA);
    __syncthreads();                         // barrier drains DMA (vmcnt 0)
    for (int kt = 0; kt < NIT; kt += 2) {
        stage(kt + 1, smB);                  // kt+1 <= NIT-1 (NIT even)
        body(smA);
        __syncthreads();
        if (kt + 2 < NIT) stage(kt + 2, smA);
        body(smB);
        __syncthreads();
    }

    // ---- row-sum reduce ----
    #pragma unroll
    for (int nt = 0; nt < 2; ++nt) {
        l_i[nt] += __shfl_xor(l_i[nt], 16);
        l_i[nt] += __shfl_xor(l_i[nt], 32);
    }
    if (quad == 0) {
        #pragma unroll
        for (int nt = 0; nt < 2; ++nt)
            lpart[(size_t)sl * TOTROWS + qrow0 + nt * 16 + lo] = l_i[nt];
    }

    // ---- coalesced epilogue: bounce O through freed LDS, full-line stores
    constexpr int OSTR = 136;                // 272 B rows (16B-aligned)
    unsigned short* obl = smA;               // 128 x 136 shorts = 34816 B
    #pragma unroll
    for (int nt = 0; nt < 2; ++nt) {
        const int row = wv * 32 + nt * 16 + lo;
        #pragma unroll
        for (int ct = 0; ct < 8; ++ct) {
            u32x2 w;
            w[0] = cvtpk(ot[nt][ct][0], ot[nt][ct][1]);
            w[1] = cvtpk(ot[nt][ct][2], ot[nt][ct][3]);
            *reinterpret_cast<u32x2*>(&obl[row * OSTR + ct * 16 + quad * 4]) = w;
        }
    }
    __syncthreads();
    {
        unsigned short* obg = opart + (size_t)sl * TOTROWS * C;
        const int row  = tid >> 1;
        const int half = tid & 1;
        const unsigned short* src = &obl[row * OSTR + half * 64];
        unsigned short*       dst = &obg[((size_t)rowb + row) * C + half * 64];
        #pragma unroll
        for (int i = 0; i < 8; ++i)
            *reinterpret_cast<uint4*>(&dst[i * 8]) =
                *reinterpret_cast<const uint4*>(&src[i * 8]);
    }

    // ---- split-K fixup: last block of the (b,qt) group combines ----
    __threadfence();                 // release this block's opart/lpart stores
    __syncthreads();                 // all threads fenced before the atomic
    if (tid == 0) {
        unsigned int old = atomicAdd(&cnt[b * 32 + qt], 1u);
        lastflag = (old == (unsigned)(nspl - 1)) ? 1u : 0u;
    }
    __syncthreads();
    if (lastflag) {
        __threadfence();             // acquire: see other blocks' stores
        #pragma unroll
        for (int it = 0; it < 16; ++it) {
            const int gid  = it * 256 + tid;          // 0..4095
            const int rloc = gid >> 5;
            const int c4   = (gid & 31) * 4;
            const size_t row = (size_t)rowb + rloc;

            float denom = 0.f;
            for (int j = 0; j < nspl; ++j)
                denom += lpart[(size_t)j * TOTROWS + row];
            float inv = 1.0f / denom;

            const size_t idx = row * C + c4;
            float a0 = 0.f, a1 = 0.f, a2 = 0.f, a3 = 0.f;
            for (int j = 0; j < nspl; ++j) {
                u32x2 o = *reinterpret_cast<const u32x2*>(
                    &opart[(size_t)j * TOTROWS * C + idx]);
                a0 += bf2f(o[0] & 0xffff);
                a1 += bf2f(o[0] >> 16);
                a2 += bf2f(o[1] & 0xffff);
                a3 += bf2f(o[1] >> 16);
            }
            float4 xv = *reinterpret_cast<const float4*>(&x[idx]);
            float4 ov;
            ov.x = xv.x + a0 * inv;
            ov.y = xv.y + a1 * inv;
            ov.z = xv.z + a2 * inv;
            ov.w = xv.w + a3 * inv;
            *reinterpret_cast<float4*>(&out[idx]) = ov;
        }
    }
}

// ---------------------------------------------------------------------------
extern "C" void kernel_launch(void* const* d_in, const int* in_sizes, int n_in,
                              void* d_out, int out_size, void* d_ws, size_t ws_size,
                              hipStream_t stream)
{
    const float* x  = (const float*)d_in[0];
    const float* Wq = (const float*)d_in[1];
    const float* bq = (const float*)d_in[2];
    const float* Wk = (const float*)d_in[3];
    const float* bk = (const float*)d_in[4];
    const float* Wv = (const float*)d_in[5];
    const float* bv = (const float*)d_in[6];
    float* out = (float*)d_out;

    // nspl=4 needs ~29 MB of ws; fall back to 2 if the workspace is small.
    const int nspl = (ws_size >= ((size_t)31 << 20)) ? 4 : 2;

    const size_t SPLIT_BYTES = (size_t)TOTROWS * C * 2;   // 4 MB
    char* ws = (char*)d_ws;
    unsigned short* opart = (unsigned short*)ws;                  // nspl*4 MB
    char* base = ws + (size_t)nspl * SPLIT_BYTES;
    unsigned short* q  = (unsigned short*)(base);                    // 4 MB
    unsigned short* k  = (unsigned short*)(base + SPLIT_BYTES);      // 4 MB
    unsigned short* vt = (unsigned short*)(base + 2 * SPLIT_BYTES);  // 4 MB (tiled)
    float*          lp = (float*)(base + 3 * SPLIT_BYTES);           // nspl*64 KB
    unsigned short* wt = (unsigned short*)(base + 3 * SPLIT_BYTES
                                           + (size_t)nspl * TOTROWS * 4); // 96 KB
    unsigned int*  cnt = (unsigned int*)((char*)wt + 3 * 16384 * 2);     // 512 B

    hipMemsetAsync(cnt, 0, 128 * sizeof(unsigned int), stream);
    wprep_kernel<<<3, 256, 0, stream>>>(Wq, Wk, Wv, wt);
    qkv_kernel<<<TOTROWS / 64, 256, 0, stream>>>(x, wt, bq, bk, bv, q, k, vt);
    attn_kernel<<<nspl * 128, 256, 0, stream>>>(q, k, vt, opart, lp, x, out, cnt);
}

// Round 9
// 132.450 us; speedup vs baseline: 1.9293x; 1.9293x over previous
//
#include <hip/hip_runtime.h>

// Problem constants: x [4, 64, 64, 128] fp32
constexpr int C       = 128;
constexpr int N       = 4096;
constexpr int BATCH   = 4;
constexpr int TOTROWS = BATCH * N;            // 16384
constexpr float SCALE = 0.08838834764831845f; // 1/sqrt(128)
constexpr float LOG2E = 1.44269504088896340736f;

constexpr int BK = 64;     // keys per iteration

typedef __attribute__((ext_vector_type(8))) short        bf16x8;
typedef __attribute__((ext_vector_type(4))) float        f32x4;
typedef __attribute__((ext_vector_type(2))) unsigned int u32x2;

__device__ inline unsigned short f2bf(float f) {   // RNE float->bf16 (scalar)
    unsigned int u = __float_as_uint(f);
    return (unsigned short)((u + 0x7FFFu + ((u >> 16) & 1u)) >> 16);
}
// packed RNE f32x2 -> bf16x2 in ONE instruction
__device__ inline unsigned int cvtpk(float a, float b) {
    unsigned int r;
    asm("v_cvt_pk_bf16_f32 %0, %1, %2" : "=v"(r) : "v"(a), "v"(b));
    return r;
}
__device__ inline float bf2f(unsigned int u) {
    return __uint_as_float(u << 16);
}
// bare v_exp_f32 (q is pre-scaled by LOG2E; no OCML range-fixup needed)
__device__ inline float fexp2(float x) {
#if __has_builtin(__builtin_amdgcn_exp2f)
    return __builtin_amdgcn_exp2f(x);
#else
    float r; asm("v_exp_f32 %0, %1\n\ts_nop 0" : "=v"(r) : "v"(x)); return r;
#endif
}
// async global->LDS DMA, 16B per lane; LDS dest = wave-uniform base + lane*16
__device__ inline void dma16(const void* g, void* l) {
    __builtin_amdgcn_global_load_lds(
        (const __attribute__((address_space(1))) void*)g,
        (__attribute__((address_space(3))) void*)l, 16, 0, 0);
}

// ---------------------------------------------------------------------------
// wprep (r8-verified): one-time W transpose (3 blocks x 256 thr), contiguous
// 16B stores. granule g of row o holds W[i][o], i = ((g&8)|((g&7)^xr))*8+e,
// xr=(o>>2)&7 — the exact swizzled LDS image qkv's MFMA reads expect.
// ---------------------------------------------------------------------------
__global__ __launch_bounds__(256)
void wprep_kernel(const float* __restrict__ Wq, const float* __restrict__ Wk,
                  const float* __restrict__ Wv, unsigned short* __restrict__ wt)
{
    const int mat = blockIdx.x;
    const float* W = (mat == 0) ? Wq : (mat == 1) ? Wk : Wv;
    const float  s = (mat == 0) ? SCALE * LOG2E : 1.0f;
    unsigned short* dst = wt + mat * 16384;

    const int t  = threadIdx.x;
    const int o  = t >> 1;             // output chan (W^T row), 0..127
    const int g0 = (t & 1) * 8;        // granule half
    const int xr = (o >> 2) & 7;
    #pragma unroll
    for (int gg = 0; gg < 8; ++gg) {
        const int g   = g0 + gg;
        const int ihi = (g & 8) | ((g & 7) ^ xr);
        const int i0  = ihi << 3;
        union { unsigned short u16[8]; uint4 v; } buf;
        #pragma unroll
        for (int e = 0; e < 8; ++e)
            buf.u16[e] = f2bf(W[(i0 + e) * 128 + o] * s);
        *reinterpret_cast<uint4*>(&dst[o * 128 + g * 8]) = buf.v;
    }
}

// ---------------------------------------------------------------------------
// round-22 qkv: PARALLEL grid (TOTROWS/64, 3) = 768 blocks (3/CU).
// r8 post-mortem: non-attn GPU time is ~60-67us; r7's qkv ran 256 blocks =
// 1 block/CU with three serial DMA->barrier->MFMA stages — nothing resident
// to hide DMA latency or barrier drains. This version: one block = 64 rows x
// ONE matrix; W-image DMA (32KB, L2-hot) issued BEFORE the x loads so HBM/L2
// latency overlaps; single barrier; 32 MFMAs/wave; verified r7 epilogues.
// LDS 32KB -> 3+ blocks/CU co-resident, independent (no lockstep).
// ---------------------------------------------------------------------------
__global__ __launch_bounds__(256, 2)
void qkv_kernel(const float* __restrict__ x, const unsigned short* __restrict__ wt,
                const float* __restrict__ bq, const float* __restrict__ bk,
                const float* __restrict__ bv,
                unsigned short* __restrict__ qo,
                unsigned short* __restrict__ ko,
                unsigned short* __restrict__ vt)
{
    __shared__ __align__(16) unsigned short wl[16384];   // 32768 B

    const int tid  = threadIdx.x;
    const int lane = tid & 63;
    const int lo   = lane & 15;
    const int quad = lane >> 4;
    const int mat  = blockIdx.y;
    const long rowbase = (long)blockIdx.x * 64 + (tid >> 6) * 16;

    // issue W-image DMA first: latency hides under the x loads below
    {
        const char* src = (const char*)(wt + mat * 16384);
        #pragma unroll
        for (int c = 0; c < 8; ++c)
            dma16(src + (c * 256 + tid) * 16, &wl[(c * 256 + tid) * 8]);
    }

    // x fragments (row = rowbase+lo, k = ks*32+quad*8), fp32->bf16 in regs.
    bf16x8 xf[4];
    {
        const float4* xr = reinterpret_cast<const float4*>(&x[(rowbase + lo) * C]);
        #pragma unroll
        for (int ks = 0; ks < 4; ++ks) {
            float4 a  = xr[ks * 8 + quad * 2];
            float4 b2 = xr[ks * 8 + quad * 2 + 1];
            union { bf16x8 v; unsigned int u[4]; } cv;
            cv.u[0] = cvtpk(a.x, a.y);
            cv.u[1] = cvtpk(a.z, a.w);
            cv.u[2] = cvtpk(b2.x, b2.y);
            cv.u[3] = cvtpk(b2.z, b2.w);
            xf[ks] = cv.v;
        }
    }

    __syncthreads();                  // drains DMA (vmcnt 0)

    if (mat < 2) {
        // q/k: D[m=outchan][n=row], A=W^T frag, B=xf -> row-major store
        f32x4 acc[8] = {};
        #pragma unroll
        for (int ks = 0; ks < 4; ++ks)
            #pragma unroll
            for (int mt = 0; mt < 8; ++mt) {
                const int rr = mt * 16 + lo;
                bf16x8 wf = *reinterpret_cast<const bf16x8*>(
                    &wl[rr * 128 + (((ks * 4 + quad) ^ ((rr >> 2) & 7)) << 3)]);
                acc[mt] = __builtin_amdgcn_mfma_f32_16x16x32_bf16(
                    wf, xf[ks], acc[mt], 0, 0, 0);
            }
        const float* bias = (mat == 0) ? bq : bk;
        const float  s    = (mat == 0) ? SCALE * LOG2E : 1.0f;
        unsigned short* out = (mat == 0) ? qo : ko;
        long row = rowbase + lo;
        #pragma unroll
        for (int mt = 0; mt < 8; ++mt) {
            float4 bb = *reinterpret_cast<const float4*>(&bias[mt * 16 + quad * 4]);
            u32x2 w;
            w[0] = cvtpk(acc[mt][0] + bb.x * s, acc[mt][1] + bb.y * s);
            w[1] = cvtpk(acc[mt][2] + bb.z * s, acc[mt][3] + bb.w * s);
            *reinterpret_cast<u32x2*>(&out[row * C + mt * 16 + quad * 4]) = w;
        }
    } else {
        // v: D[m=row][n=chan], A=xf, B=W^T frag -> tiled transposed store
        f32x4 acc[8] = {};
        #pragma unroll
        for (int ks = 0; ks < 4; ++ks)
            #pragma unroll
            for (int ct = 0; ct < 8; ++ct) {
                const int rr = ct * 16 + lo;
                bf16x8 wf = *reinterpret_cast<const bf16x8*>(
                    &wl[rr * 128 + (((ks * 4 + quad) ^ ((rr >> 2) & 7)) << 3)]);
                acc[ct] = __builtin_amdgcn_mfma_f32_16x16x32_bf16(
                    xf[ks], wf, acc[ct], 0, 0, 0);
            }
        const int b = (int)(rowbase >> 12);
        const int nbase = (int)(rowbase & (N - 1));
        const int n0   = nbase + quad * 4;
        const int nblk = n0 >> 6;
        #pragma unroll
        for (int ct = 0; ct < 8; ++ct) {
            int chan = ct * 16 + lo;
            float bb = bv[chan];
            u32x2 w;
            w[0] = cvtpk(acc[ct][0] + bb, acc[ct][1] + bb);
            w[1] = cvtpk(acc[ct][2] + bb, acc[ct][3] + bb);
            *reinterpret_cast<u32x2*>(
                &vt[(((size_t)b * 64 + nblk) * 128 + chan) * 64 + (n0 & 63)]) = w;
        }
    }
}

// ---------------------------------------------------------------------------
// Flash attention — r3/r7-verified body (46.4us), UNCHANGED. Split-K fixup
// reverted (r8: per-block device-scope fences = serialized L2 writebacks,
// 46->188us). Combine stays a separate kernel.
// ---------------------------------------------------------------------------
__global__ __launch_bounds__(256, 2)
void attn_kernel(const unsigned short* __restrict__ q,
                 const unsigned short* __restrict__ k,
                 const unsigned short* __restrict__ vt,
                 unsigned short* __restrict__ opart,
                 float* __restrict__ lpart)
{
    // buffer A: K0 @0 (8192), V0 @8192 (8192), pad to 17472 shorts;
    //           reused as O-bounce (128 x 136 shorts) in the epilogue
    __shared__ __align__(16) unsigned short smA[17472];  // 34944 B
    __shared__ __align__(16) unsigned short smB[16384];  // 32768 B (K1,V1)
    __shared__ __align__(16) unsigned short smP[4096];   //  8192 B (4 waves x 32x32)

    const int tid  = threadIdx.x;
    const int wv   = tid >> 6;          // 0..3
    const int lane = tid & 63;
    const int lo   = lane & 15;
    const int quad = lane >> 4;

    const int nspl = (int)(gridDim.x >> 7);      // 512 -> 4, 256 -> 2
    const int id   = blockIdx.x;
    int b, sl, qt;
    if (nspl == 4) {         // id%8 = b*2 + (sl&1): pins (batch,parity) to XCD
        b  = (id >> 1) & 3;
        sl = (id & 1) | (((id >> 3) & 1) << 1);
        qt = id >> 4;        // 0..31
    } else {
        b  = (id >> 1) & 3;
        sl = id & 1;
        qt = id >> 3;
    }
    const int NIT  = (N / nspl) / BK;            // 16 (nspl=4), even
    const int koff = sl * (N / nspl);

    const int    rowb  = b * N + qt * 128;       // block's first q-row (global)
    const size_t qrow0 = (size_t)rowb + wv * 32; // wave's first q-row
    const char* kb8 = (const char*)(k  + ((size_t)b * N + koff) * C);
    const char* vb8 = (const char*)(vt + ((size_t)b * 64 + (koff >> 6)) * (size_t)(128 * 64));

    unsigned short* PW = smP + wv * 1024;        // wave-private 32x32 P tile

    // Q fragments (B operand): qf[nt][ks], row = qrow0 + nt*16 + lo
    bf16x8 qf[2][4];
    #pragma unroll
    for (int nt = 0; nt < 2; ++nt)
        #pragma unroll
        for (int ks = 0; ks < 4; ++ks)
            qf[nt][ks] = *reinterpret_cast<const bf16x8*>(
                &q[(qrow0 + nt * 16 + lo) * C + ks * 32 + quad * 8]);

    // DMA source offsets (bytes, kt-invariant), pre-swizzled so that linear
    // LDS granule G holds swizzled global granule; reads apply the same XOR.
    int offK[4], offV[4];
    #pragma unroll
    for (int c = 0; c < 4; ++c) {
        int G  = (wv * 4 + c) * 64 + lane;
        int kr = G >> 4;                              // K: 64 rows x 16 granules
        offK[c] = kr * 256 + (((G & 15) ^ (kr & 7)) << 4);
        int vr = G >> 3;                              // V: 128 rows x 8 granules
        offV[c] = vr * 128 + (((G & 7) ^ (vr & 7)) << 4);
    }

    auto stage = [&](int kt, unsigned short* dstKV) {
        const char* kt8 = kb8 + kt * 16384;
        const char* vt8 = vb8 + kt * 16384;
        #pragma unroll
        for (int c = 0; c < 4; ++c)
            dma16(kt8 + offK[c], dstKV + (wv * 4 + c) * 512);
        #pragma unroll
        for (int c = 0; c < 4; ++c)
            dma16(vt8 + offV[c], dstKV + 8192 + (wv * 4 + c) * 512);
    };

    float l_i[2] = { 0.f, 0.f };
    f32x4 ot[2][8] = {};   // O^T: col = qrow nt*16+lo, regs = chan ct*16+quad*4+r

    auto body = [&](const unsigned short* base) {
        const unsigned short* kc = base;
        const unsigned short* vc = base + 8192;

        // ---- S^T = K.Q^T : st[mt][nt], key = mt*16+quad*4+r, qrow = nt*16+lo
        f32x4 st[4][2] = {};
        #pragma unroll
        for (int ks = 0; ks < 4; ++ks)
            #pragma unroll
            for (int mt = 0; mt < 4; ++mt) {
                const bf16x8 kf = *reinterpret_cast<const bf16x8*>(
                    &kc[(mt * 16 + lo) * 128 + (((ks * 4 + quad) ^ (lo & 7)) << 3)]);
                #pragma unroll
                for (int nt = 0; nt < 2; ++nt)
                    st[mt][nt] = __builtin_amdgcn_mfma_f32_16x16x32_bf16(
                        kf, qf[nt][ks], st[mt][nt], 0, 0, 0);
            }

        // ---- per 32-key half: softmax numerator (fixed m=0) + PV ----
        #pragma unroll
        for (int h = 0; h < 2; ++h) {
            #pragma unroll
            for (int nt = 0; nt < 2; ++nt) {
                const int prow = nt * 16 + lo;
                float ps = 0.f;
                #pragma unroll
                for (int m = 0; m < 2; ++m) {
                    f32x4 s = st[2 * h + m][nt];
                    float p0 = fexp2(s[0]);
                    float p1 = fexp2(s[1]);
                    float p2 = fexp2(s[2]);
                    float p3 = fexp2(s[3]);
                    ps += (p0 + p1) + (p2 + p3);
                    u32x2 w;
                    w[0] = cvtpk(p0, p1);
                    w[1] = cvtpk(p2, p3);
                    *reinterpret_cast<u32x2*>(
                        &PW[prow * 32 + (((2 * m + (quad >> 1)) ^ (prow & 3)) << 3)
                            + (quad & 1) * 4]) = w;
                }
                l_i[nt] += ps;
            }
            bf16x8 pf[2];
            #pragma unroll
            for (int nt = 0; nt < 2; ++nt) {
                const int prow = nt * 16 + lo;
                pf[nt] = *reinterpret_cast<const bf16x8*>(
                    &PW[prow * 32 + ((quad ^ (prow & 3)) << 3)]);
            }
            #pragma unroll
            for (int ct = 0; ct < 8; ++ct) {
                const bf16x8 vf = *reinterpret_cast<const bf16x8*>(
                    &vc[(ct * 16 + lo) * 64 + (((h * 4 + quad) ^ (lo & 7)) << 3)]);
                #pragma unroll
                for (int nt = 0; nt < 2; ++nt)
                    ot[nt][ct] = __builtin_amdgcn_mfma_f32_16x16x32_bf16(
                        vf, pf[nt], ot[nt][ct], 0, 0, 0);
            }
        }
    };

    // ---- pipeline: stage next tile (async DMA) || compute current ----
    stage(0, smA);
    __syncthreads();                         // barrier drains DMA (vmcnt 0)
    for (int kt = 0; kt < NIT; kt += 2) {
        stage(kt + 1, smB);                  // kt+1 <= NIT-1 (NIT even)
        body(smA);
        __syncthreads();
        if (kt + 2 < NIT) stage(kt + 2, smA);
        body(smB);
        __syncthreads();
    }

    // ---- row-sum reduce ----
    #pragma unroll
    for (int nt = 0; nt < 2; ++nt) {
        l_i[nt] += __shfl_xor(l_i[nt], 16);
        l_i[nt] += __shfl_xor(l_i[nt], 32);
    }
    if (quad == 0) {
        #pragma unroll
        for (int nt = 0; nt < 2; ++nt)
            lpart[(size_t)sl * TOTROWS + qrow0 + nt * 16 + lo] = l_i[nt];
    }

    // ---- coalesced epilogue: bounce O through freed LDS, full-line stores
    constexpr int OSTR = 136;                // 272 B rows (16B-aligned)
    unsigned short* obl = smA;               // 128 x 136 shorts = 34816 B
    #pragma unroll
    for (int nt = 0; nt < 2; ++nt) {
        const int row = wv * 32 + nt * 16 + lo;
        #pragma unroll
        for (int ct = 0; ct < 8; ++ct) {
            u32x2 w;
            w[0] = cvtpk(ot[nt][ct][0], ot[nt][ct][1]);
            w[1] = cvtpk(ot[nt][ct][2], ot[nt][ct][3]);
            *reinterpret_cast<u32x2*>(&obl[row * OSTR + ct * 16 + quad * 4]) = w;
        }
    }
    __syncthreads();
    {
        unsigned short* obg = opart + (size_t)sl * TOTROWS * C;
        const int row  = tid >> 1;
        const int half = tid & 1;
        const unsigned short* src = &obl[row * OSTR + half * 64];
        unsigned short*       dst = &obg[((size_t)rowb + row) * C + half * 64];
        #pragma unroll
        for (int i = 0; i < 8; ++i)
            *reinterpret_cast<uint4*>(&dst[i * 8]) =
                *reinterpret_cast<const uint4*>(&src[i * 8]);
    }
}

// ---------------------------------------------------------------------------
// Combine nspl splits + residual: out = x + (sum_j O_j) / (sum_j l_j)
// ---------------------------------------------------------------------------
__global__ __launch_bounds__(256)
void combine_kernel(const float* __restrict__ x,
                    const unsigned short* __restrict__ opart,
                    const float* __restrict__ lpart,
                    float* __restrict__ out, int nspl)
{
    int gid = blockIdx.x * 256 + threadIdx.x;     // TOTROWS*32
    int row = gid >> 5;
    int c4  = (gid & 31) * 4;

    float denom = 0.f;
    for (int j = 0; j < nspl; ++j) denom += lpart[(size_t)j * TOTROWS + row];
    float inv = 1.0f / denom;

    size_t idx = (size_t)row * C + c4;
    float a0 = 0.f, a1 = 0.f, a2 = 0.f, a3 = 0.f;
    for (int j = 0; j < nspl; ++j) {
        u32x2 o = *reinterpret_cast<const u32x2*>(
            &opart[(size_t)j * TOTROWS * C + idx]);
        a0 += bf2f(o[0] & 0xffff);
        a1 += bf2f(o[0] >> 16);
        a2 += bf2f(o[1] & 0xffff);
        a3 += bf2f(o[1] >> 16);
    }
    float4 xv = *reinterpret_cast<const float4*>(&x[idx]);
    float4 o;
    o.x = xv.x + a0 * inv;
    o.y = xv.y + a1 * inv;
    o.z = xv.z + a2 * inv;
    o.w = xv.w + a3 * inv;
    *reinterpret_cast<float4*>(&out[idx]) = o;
}

// ---------------------------------------------------------------------------
extern "C" void kernel_launch(void* const* d_in, const int* in_sizes, int n_in,
                              void* d_out, int out_size, void* d_ws, size_t ws_size,
                              hipStream_t stream)
{
    const float* x  = (const float*)d_in[0];
    const float* Wq = (const float*)d_in[1];
    const float* bq = (const float*)d_in[2];
    const float* Wk = (const float*)d_in[3];
    const float* bk = (const float*)d_in[4];
    const float* Wv = (const float*)d_in[5];
    const float* bv = (const float*)d_in[6];
    float* out = (float*)d_out;

    // nspl=4 needs ~29 MB of ws; fall back to 2 if the workspace is small.
    const int nspl = (ws_size >= ((size_t)31 << 20)) ? 4 : 2;

    const size_t SPLIT_BYTES = (size_t)TOTROWS * C * 2;   // 4 MB
    char* ws = (char*)d_ws;
    unsigned short* opart = (unsigned short*)ws;                  // nspl*4 MB
    char* base = ws + (size_t)nspl * SPLIT_BYTES;
    unsigned short* q  = (unsigned short*)(base);                    // 4 MB
    unsigned short* k  = (unsigned short*)(base + SPLIT_BYTES);      // 4 MB
    unsigned short* vt = (unsigned short*)(base + 2 * SPLIT_BYTES);  // 4 MB (tiled)
    float*          lp = (float*)(base + 3 * SPLIT_BYTES);           // nspl*64 KB
    unsigned short* wt = (unsigned short*)(base + 3 * SPLIT_BYTES
                                           + (size_t)nspl * TOTROWS * 4); // 96 KB

    wprep_kernel<<<3, 256, 0, stream>>>(Wq, Wk, Wv, wt);
    qkv_kernel<<<dim3(TOTROWS / 64, 3), 256, 0, stream>>>(
        x, wt, bq, bk, bv, q, k, vt);
    attn_kernel<<<nspl * 128, 256, 0, stream>>>(q, k, vt, opart, lp);
    combine_kernel<<<TOTROWS * 32 / 256, 256, 0, stream>>>(x, opart, lp, out, nspl);
}